// Round 2
// baseline (240.316 us; speedup 1.0000x reference)
//
#include <hip/hip_runtime.h>
#include <cstddef>

typedef short s4v __attribute__((ext_vector_type(4)));
typedef short s8v __attribute__((ext_vector_type(8)));
typedef float f4v __attribute__((ext_vector_type(4)));

__device__ __forceinline__ unsigned short f2bf(float f) {
    union { float f; unsigned u; } v; v.f = f;
    unsigned r = v.u + 0x7fff + ((v.u >> 16) & 1);
    return (unsigned short)(r >> 16);
}
__device__ __forceinline__ float bf2f(unsigned short u) {
    union { unsigned u; float f; } v; v.u = ((unsigned)u) << 16;
    return v.f;
}

// async global->LDS, 16B per lane. LDS dest is wave-uniform base + lane*16.
__device__ __forceinline__ void gl_lds16(const void* g, void* l) {
    __builtin_amdgcn_global_load_lds(
        (const __attribute__((address_space(1))) void*)g,
        (__attribute__((address_space(3))) void*)l, 16, 0, 0);
}

#define QSC   0.18033688011112043f   /* 0.125 * log2(e) */
#define EOFF  23.082320654223414f    /* 16 * log2(e) */

// ---------------------------------------------------------------------------
// Fused f32 -> bf16 conversion for x, qkv_w, proj_w (one launch).
// 8 elems/thread; ranges in 8-elem groups: x 786432 | qkv_w 221184 | proj_w 73728
// ---------------------------------------------------------------------------
__global__ __launch_bounds__(256) void to_bf16_all(
    const float* __restrict__ x, const float* __restrict__ qw,
    const float* __restrict__ pw, unsigned short* __restrict__ xd,
    unsigned short* __restrict__ qd, unsigned short* __restrict__ pd)
{
    int i = blockIdx.x * 256 + threadIdx.x;
    const float* s; unsigned short* d; int j;
    if (i < 786432)       { s = x;  d = xd; j = i; }
    else if (i < 1007616) { s = qw; d = qd; j = i - 786432; }
    else                  { s = pw; d = pd; j = i - 1007616; }
    float4 f0 = ((const float4*)s)[j * 2];
    float4 f1 = ((const float4*)s)[j * 2 + 1];
    uint4 pk;
    pk.x = (unsigned)f2bf(f0.x) | ((unsigned)f2bf(f0.y) << 16);
    pk.y = (unsigned)f2bf(f0.z) | ((unsigned)f2bf(f0.w) << 16);
    pk.z = (unsigned)f2bf(f1.x) | ((unsigned)f2bf(f1.y) << 16);
    pk.w = (unsigned)f2bf(f1.z) | ((unsigned)f2bf(f1.w) << 16);
    ((uint4*)d)[j] = pk;
}

// ---------------------------------------------------------------------------
// bf16 MFMA GEMM, m97 structure: 128x128 tile, BK=32, 256 thr = 4 waves.
// QKV epilogue: q bf16 (pre-scaled by 0.125*log2e for exp2 softmax), k bf16
// row-major, V written TRANSPOSED ([bh][d][tok]) via b64 stores.
// ---------------------------------------------------------------------------
__global__ __launch_bounds__(256) void qkv_gemm_mfma(
    const unsigned short* __restrict__ A, const unsigned short* __restrict__ W,
    const float* __restrict__ bias,
    unsigned short* __restrict__ qb, unsigned short* __restrict__ kb,
    unsigned short* __restrict__ vt)
{
    __shared__ __align__(16) unsigned short As[128 * 32];
    __shared__ __align__(16) unsigned short Bs[128 * 32];
    const int t     = threadIdx.x;
    const int bc    = blockIdx.x;   // N = 2304 -> 18
    const int br    = blockIdx.y;   // M = 8192 -> 64
    const int wv    = t >> 6;
    const int lane  = t & 63;
    const int col16 = lane & 15;
    const int quad  = lane >> 4;
    const int w4    = lane >> 2;
    const int k8    = (lane & 3) << 3;
    const int mw    = wv >> 1, nw = wv & 1;

    const unsigned short* Ag = A + (size_t)(br * 128 + (wv << 5) + w4) * 768 + k8;
    const unsigned short* Wg = W + (size_t)(bc * 128 + (wv << 5) + w4) * 768 + k8;
    unsigned short* Asw = &As[(wv << 5) * 32];
    unsigned short* Bsw = &Bs[(wv << 5) * 32];

    f4v acc[4][4];
#pragma unroll
    for (int mt = 0; mt < 4; ++mt)
#pragma unroll
        for (int nt = 0; nt < 4; ++nt) {
            acc[mt][nt][0] = 0.f; acc[mt][nt][1] = 0.f;
            acc[mt][nt][2] = 0.f; acc[mt][nt][3] = 0.f;
        }

    for (int k0 = 0; k0 < 768; k0 += 32) {
        __syncthreads();
        gl_lds16(Ag + k0,             Asw);
        gl_lds16(Ag + k0 + 16 * 768,  Asw + 16 * 32);
        gl_lds16(Wg + k0,             Bsw);
        gl_lds16(Wg + k0 + 16 * 768,  Bsw + 16 * 32);
        __syncthreads();

        s8v a[4], b[4];
#pragma unroll
        for (int mt = 0; mt < 4; ++mt)
            a[mt] = *(const s8v*)&As[(mw * 64 + mt * 16 + col16) * 32 + quad * 8];
#pragma unroll
        for (int nt = 0; nt < 4; ++nt)
            b[nt] = *(const s8v*)&Bs[(nw * 64 + nt * 16 + col16) * 32 + quad * 8];
#pragma unroll
        for (int mt = 0; mt < 4; ++mt)
#pragma unroll
            for (int nt = 0; nt < 4; ++nt)
                acc[mt][nt] = __builtin_amdgcn_mfma_f32_16x16x32_bf16(
                    a[mt], b[nt], acc[mt][nt], 0, 0, 0);
    }

    const int which = bc / 6;
    const int cb    = (bc % 6) * 128 + nw * 64;
    const int m0    = br * 128 + mw * 64 + quad * 4;
    if (which == 2) {
        // V transposed: [bh][d][tok], 4 consecutive toks per b64 store
#pragma unroll
        for (int nt = 0; nt < 4; ++nt) {
            int c    = cb + nt * 16 + col16;
            int head = c >> 6, d = c & 63;
            float bv = bias[1536 + c];
#pragma unroll
            for (int mt = 0; mt < 4; ++mt) {
                int mb  = m0 + mt * 16;
                int bbk = mb >> 10, tok = mb & 1023;
                uint2 pk;
                pk.x = (unsigned)f2bf(acc[mt][nt][0] + bv)
                     | ((unsigned)f2bf(acc[mt][nt][1] + bv) << 16);
                pk.y = (unsigned)f2bf(acc[mt][nt][2] + bv)
                     | ((unsigned)f2bf(acc[mt][nt][3] + bv) << 16);
                *(uint2*)&vt[((size_t)(bbk * 12 + head)) * 65536 + (size_t)d * 1024 + tok] = pk;
            }
        }
    } else {
        // q carries 0.125*log2e so downstream softmax can use exp2 directly
        const float sc = (which == 0) ? QSC : 1.0f;
        unsigned short* dst = (which == 0) ? qb : kb;
#pragma unroll
        for (int nt = 0; nt < 4; ++nt) {
            int c    = cb + nt * 16 + col16;
            int head = c >> 6, d = c & 63;
            float bv = bias[which * 768 + c];
#pragma unroll
            for (int mt = 0; mt < 4; ++mt) {
#pragma unroll
                for (int i = 0; i < 4; ++i) {
                    int m   = m0 + mt * 16 + i;
                    int bbk = m >> 10, tok = m & 1023;
                    dst[(((size_t)(bbk * 12 + head) << 10) + tok) * 64 + d] =
                        f2bf((acc[mt][nt][i] + bv) * sc);
                }
            }
        }
    }
}

__global__ __launch_bounds__(256) void proj_gemm_mfma(
    const unsigned short* __restrict__ A, const unsigned short* __restrict__ W,
    const float* __restrict__ bias, float* __restrict__ Out)
{
    __shared__ __align__(16) unsigned short As[128 * 32];
    __shared__ __align__(16) unsigned short Bs[128 * 32];
    const int t     = threadIdx.x;
    const int bc    = blockIdx.x;
    const int br    = blockIdx.y;
    const int wv    = t >> 6;
    const int lane  = t & 63;
    const int col16 = lane & 15;
    const int quad  = lane >> 4;
    const int w4    = lane >> 2;
    const int k8    = (lane & 3) << 3;
    const int mw    = wv >> 1, nw = wv & 1;

    const unsigned short* Ag = A + (size_t)(br * 128 + (wv << 5) + w4) * 768 + k8;
    const unsigned short* Wg = W + (size_t)(bc * 128 + (wv << 5) + w4) * 768 + k8;
    unsigned short* Asw = &As[(wv << 5) * 32];
    unsigned short* Bsw = &Bs[(wv << 5) * 32];

    f4v acc[4][4];
#pragma unroll
    for (int mt = 0; mt < 4; ++mt)
#pragma unroll
        for (int nt = 0; nt < 4; ++nt) {
            acc[mt][nt][0] = 0.f; acc[mt][nt][1] = 0.f;
            acc[mt][nt][2] = 0.f; acc[mt][nt][3] = 0.f;
        }

    for (int k0 = 0; k0 < 768; k0 += 32) {
        __syncthreads();
        gl_lds16(Ag + k0,             Asw);
        gl_lds16(Ag + k0 + 16 * 768,  Asw + 16 * 32);
        gl_lds16(Wg + k0,             Bsw);
        gl_lds16(Wg + k0 + 16 * 768,  Bsw + 16 * 32);
        __syncthreads();

        s8v a[4], b[4];
#pragma unroll
        for (int mt = 0; mt < 4; ++mt)
            a[mt] = *(const s8v*)&As[(mw * 64 + mt * 16 + col16) * 32 + quad * 8];
#pragma unroll
        for (int nt = 0; nt < 4; ++nt)
            b[nt] = *(const s8v*)&Bs[(nw * 64 + nt * 16 + col16) * 32 + quad * 8];
#pragma unroll
        for (int mt = 0; mt < 4; ++mt)
#pragma unroll
            for (int nt = 0; nt < 4; ++nt)
                acc[mt][nt] = __builtin_amdgcn_mfma_f32_16x16x32_bf16(
                    a[mt], b[nt], acc[mt][nt], 0, 0, 0);
    }

    const int m0 = br * 128 + mw * 64 + quad * 4;
#pragma unroll
    for (int nt = 0; nt < 4; ++nt) {
        int c    = bc * 128 + nw * 64 + nt * 16 + col16;
        float bv = bias[c];
#pragma unroll
        for (int mt = 0; mt < 4; ++mt) {
#pragma unroll
            for (int i = 0; i < 4; ++i) {
                int m = m0 + mt * 16 + i;
                Out[(size_t)m * 768 + c] = acc[mt][nt][i] + bv;
            }
        }
    }
}

// ---------------------------------------------------------------------------
// Bias-table precompute via MFMA (Q bf16, pre-scaled by 0.125*log2e — the
// log2e factor flows into qh/qw exactly as the reference's q*scale does).
// ---------------------------------------------------------------------------
__global__ __launch_bounds__(256) void bias_prep_mfma(
    const unsigned short* __restrict__ Q, const float* __restrict__ Rh,
    const float* __restrict__ Rw, unsigned short* __restrict__ qhb,
    unsigned short* __restrict__ qwb)
{
    __shared__ __align__(16) char smem[36864];
    unsigned short (*Qs)[72]  = (unsigned short (*)[72])smem;
    unsigned short (*Rs)[72]  = (unsigned short (*)[72])(smem + 18432);
    unsigned short (*Wsm)[72] = (unsigned short (*)[72])(smem + 27648);
    float (*G)[66]            = (float (*)[66])smem;

    const int t    = threadIdx.x;
    const int tc8  = blockIdx.x;   // 0..7 : 128-token chunk
    const int bh   = blockIdx.y;   // 0..95
    const int tok0 = tc8 << 7;

    // stage Q (bf16 global, coalesced uint4 copies)
    for (int id = t; id < 1024; id += 256) {
        int row = id >> 3, g8 = (id & 7) << 3;
        *(uint4*)&Qs[row][g8] =
            *(const uint4*)(Q + ((size_t)bh * 1024 + tok0 + row) * 64 + g8);
    }
    // stage Rh, Rw -> bf16 LDS; row 63 zeroed
    for (int id = t; id < 512; id += 256) {
        int row = id >> 3, g8 = (id & 7) << 3;
        unsigned short* dh = &Rs[row][g8];
        unsigned short* dw = &Wsm[row][g8];
        if (row < 63) {
            const float* sh = Rh + row * 64 + g8;
            const float* sw = Rw + row * 64 + g8;
            float4 a = *(const float4*)sh; float4 b = *(const float4*)(sh + 4);
            float4 c = *(const float4*)sw; float4 d = *(const float4*)(sw + 4);
            dh[0] = f2bf(a.x); dh[1] = f2bf(a.y); dh[2] = f2bf(a.z); dh[3] = f2bf(a.w);
            dh[4] = f2bf(b.x); dh[5] = f2bf(b.y); dh[6] = f2bf(b.z); dh[7] = f2bf(b.w);
            dw[0] = f2bf(c.x); dw[1] = f2bf(c.y); dw[2] = f2bf(c.z); dw[3] = f2bf(c.w);
            dw[4] = f2bf(d.x); dw[5] = f2bf(d.y); dw[6] = f2bf(d.z); dw[7] = f2bf(d.w);
        } else {
#pragma unroll
            for (int j = 0; j < 8; ++j) { dh[j] = 0; dw[j] = 0; }
        }
    }
    __syncthreads();

    const int wv    = t >> 6;
    const int lane  = t & 63;
    const int col16 = lane & 15;
    const int quad  = lane >> 4;
    const int r0    = wv << 5;

    s8v qa[2][2], rb[4][2], wb[4][2];
#pragma unroll
    for (int mt = 0; mt < 2; ++mt)
#pragma unroll
        for (int kc = 0; kc < 2; ++kc)
            qa[mt][kc] = *(const s8v*)&Qs[r0 + mt * 16 + col16][kc * 32 + quad * 8];
#pragma unroll
    for (int nt = 0; nt < 4; ++nt)
#pragma unroll
        for (int kc = 0; kc < 2; ++kc) {
            rb[nt][kc] = *(const s8v*)&Rs[nt * 16 + col16][kc * 32 + quad * 8];
            wb[nt][kc] = *(const s8v*)&Wsm[nt * 16 + col16][kc * 32 + quad * 8];
        }

    f4v ah[2][4], aw[2][4];
#pragma unroll
    for (int mt = 0; mt < 2; ++mt)
#pragma unroll
        for (int nt = 0; nt < 4; ++nt) {
            f4v z; z[0] = 0.f; z[1] = 0.f; z[2] = 0.f; z[3] = 0.f;
            ah[mt][nt] = z; aw[mt][nt] = z;
        }
#pragma unroll
    for (int mt = 0; mt < 2; ++mt)
#pragma unroll
        for (int nt = 0; nt < 4; ++nt) {
            ah[mt][nt] = __builtin_amdgcn_mfma_f32_16x16x32_bf16(qa[mt][0], rb[nt][0], ah[mt][nt], 0, 0, 0);
            ah[mt][nt] = __builtin_amdgcn_mfma_f32_16x16x32_bf16(qa[mt][1], rb[nt][1], ah[mt][nt], 0, 0, 0);
            aw[mt][nt] = __builtin_amdgcn_mfma_f32_16x16x32_bf16(qa[mt][0], wb[nt][0], aw[mt][nt], 0, 0, 0);
            aw[mt][nt] = __builtin_amdgcn_mfma_f32_16x16x32_bf16(qa[mt][1], wb[nt][1], aw[mt][nt], 0, 0, 0);
        }
    __syncthreads();

    // ---- G_h: C-layout -> gather -> store ----
#pragma unroll
    for (int mt = 0; mt < 2; ++mt)
#pragma unroll
        for (int nt = 0; nt < 4; ++nt)
#pragma unroll
            for (int i = 0; i < 4; ++i)
                G[r0 + mt * 16 + quad * 4 + i][nt * 16 + col16] = ah[mt][nt][i];
    __syncthreads();
    for (int id = t; id < 2048; id += 256) {
        int tok = id >> 4, c2 = (id & 15) << 1;
        int i_img = (tc8 << 2) + (tok >> 5);
        float g0 = G[tok][i_img - c2 + 31];
        float g1 = G[tok][i_img - c2 + 30];
        unsigned pk = (unsigned)f2bf(g0) | ((unsigned)f2bf(g1) << 16);
        *(unsigned*)&qhb[(((size_t)bh << 10) + tok0 + tok) * 32 + c2] = pk;
    }
    __syncthreads();

    // ---- G_w ----
#pragma unroll
    for (int mt = 0; mt < 2; ++mt)
#pragma unroll
        for (int nt = 0; nt < 4; ++nt)
#pragma unroll
            for (int i = 0; i < 4; ++i)
                G[r0 + mt * 16 + quad * 4 + i][nt * 16 + col16] = aw[mt][nt][i];
    __syncthreads();
    for (int id = t; id < 2048; id += 256) {
        int tok = id >> 4, c2 = (id & 15) << 1;
        int j = tok & 31;
        float g0 = G[tok][j - c2 + 31];
        float g1 = G[tok][j - c2 + 30];
        unsigned pk = (unsigned)f2bf(g0) | ((unsigned)f2bf(g1) << 16);
        *(unsigned*)&qwb[(((size_t)bh << 10) + tok0 + tok) * 32 + c2] = pk;
    }
}

// ---------------------------------------------------------------------------
// MFMA flash attention, LDS-staged K/V.
//  R11 (bisect): ONLY the exp2 refold vs the 240µs baseline —
//  q carries 0.125*log2e, -16*log2e folded into qh_s staging, inner loop is
//  2 adds + v_exp_f32 per score (was add+sub+mul+exp). All f2bf bit-twiddle
//  packing retained (cvt_pk asm reverted — R1 failure suspect).
// ---------------------------------------------------------------------------
__global__ __launch_bounds__(256, 4) void attn_mfma(
    const unsigned short* __restrict__ Q, const unsigned short* __restrict__ K,
    const unsigned short* __restrict__ Vt,
    const unsigned short* __restrict__ qhb, const unsigned short* __restrict__ qwb,
    unsigned short* __restrict__ Out)
{
    const int t  = threadIdx.x;
    const int id  = blockIdx.x;           // 0..1535
    const int xcd = id & 7;
    const int wq  = id >> 3;
    const int bh  = xcd * 12 + (wq % 12);
    const int qt2 = wq / 12;
    const int b   = bh / 12;
    const int h   = bh - b * 12;
    const int q0  = qt2 << 6;

    __shared__ __align__(16) unsigned short Ks[64 * 72];
    __shared__ __align__(16) unsigned short Vs[64 * 72];
    __shared__ __align__(16) unsigned short Pl[64 * 68];
    __shared__ float qh_s[64][33];

    const unsigned short* Kp = K  + (size_t)bh * 65536;
    const unsigned short* Vp = Vt + (size_t)bh * 65536;

    {
        const unsigned* qhp = (const unsigned*)(qhb + ((size_t)bh * 1024 + q0) * 32);
        for (int i2 = t; i2 < 1024; i2 += 256) {
            int row = i2 >> 4, c2 = (i2 & 15) << 1;
            unsigned ph = qhp[i2];
            qh_s[row][c2]     = bf2f((unsigned short)(ph & 0xffff)) - EOFF;
            qh_s[row][c2 + 1] = bf2f((unsigned short)(ph >> 16))    - EOFF;
        }
    }

    const int wv    = t >> 6;
    const int lane  = t & 63;
    const int col16 = lane & 15;
    const int quad  = lane >> 4;
    const int qrow0 = wv << 4;

    // Q A-frags: direct bf16 loads
    s8v qa0, qa1;
    {
        const unsigned short* qsrc =
            Q + ((size_t)bh * 1024 + q0 + qrow0 + col16) * 64 + quad * 8;
        qa0 = *(const s8v*)qsrc;
        qa1 = *(const s8v*)(qsrc + 32);
    }

    float qwr[4][2];
#pragma unroll
    for (int i = 0; i < 4; ++i) {
        size_t row = (size_t)bh * 1024 + q0 + qrow0 + quad * 4 + i;
        qwr[i][0] = bf2f(qwb[row * 32 + col16]);
        qwr[i][1] = bf2f(qwb[row * 32 + col16 + 16]);
    }

    {
        uint4 pk0, pk1, pv0, pv1;
        int e0 = t * 8, e1 = t * 8 + 2048;
        pk0 = *(const uint4*)(Kp + e0);
        pk1 = *(const uint4*)(Kp + e1);
        pv0 = *(const uint4*)(Vp + (size_t)(e0 >> 6) * 1024 + (e0 & 63));
        pv1 = *(const uint4*)(Vp + (size_t)(e1 >> 6) * 1024 + (e1 & 63));
        *(uint4*)&Ks[(e0 >> 6) * 72 + (e0 & 63)] = pk0;
        *(uint4*)&Ks[(e1 >> 6) * 72 + (e1 & 63)] = pk1;
        *(uint4*)&Vs[(e0 >> 6) * 72 + (e0 & 63)] = pv0;
        *(uint4*)&Vs[(e1 >> 6) * 72 + (e1 & 63)] = pv1;
    }
    __syncthreads();

    f4v o[4];
#pragma unroll
    for (int nt = 0; nt < 4; ++nt) { o[nt][0] = 0.f; o[nt][1] = 0.f; o[nt][2] = 0.f; o[nt][3] = 0.f; }
    float lp[4] = {0.f, 0.f, 0.f, 0.f};

    const int e0 = t * 8, e1 = t * 8 + 2048;
    for (int kt = 0; kt < 16; ++kt) {
        uint4 pk0, pk1, pv0, pv1;
        if (kt < 15) {
            const int k0n = (kt + 1) << 6;
            pk0 = *(const uint4*)(Kp + (size_t)k0n * 64 + e0);
            pk1 = *(const uint4*)(Kp + (size_t)k0n * 64 + e1);
            pv0 = *(const uint4*)(Vp + (size_t)(e0 >> 6) * 1024 + k0n + (e0 & 63));
            pv1 = *(const uint4*)(Vp + (size_t)(e1 >> 6) * 1024 + k0n + (e1 & 63));
        }

        f4v s4a[4];
#pragma unroll
        for (int nt = 0; nt < 4; ++nt) {
            s8v b0 = *(const s8v*)&Ks[(nt * 16 + col16) * 72 + quad * 8];
            s8v b1 = *(const s8v*)&Ks[(nt * 16 + col16) * 72 + 32 + quad * 8];
            f4v acc; acc[0] = 0.f; acc[1] = 0.f; acc[2] = 0.f; acc[3] = 0.f;
            acc = __builtin_amdgcn_mfma_f32_16x16x32_bf16(qa0, b0, acc, 0, 0, 0);
            acc = __builtin_amdgcn_mfma_f32_16x16x32_bf16(qa1, b1, acc, 0, 0, 0);
            s4a[nt] = acc;
        }

        float qh0[4], qh1[4];
#pragma unroll
        for (int i = 0; i < 4; ++i) {
            qh0[i] = qh_s[qrow0 + quad * 4 + i][(kt << 1) + 0];
            qh1[i] = qh_s[qrow0 + quad * 4 + i][(kt << 1) + 1];
        }

#pragma unroll
        for (int nt = 0; nt < 4; ++nt) {
#pragma unroll
            for (int i = 0; i < 4; ++i) {
                float s  = s4a[nt][i] + ((nt < 2) ? qh0[i] : qh1[i]) + qwr[i][nt & 1];
                float pe = __builtin_amdgcn_exp2f(s);
                lp[i] += pe;
                Pl[(qrow0 + quad * 4 + i) * 68 + nt * 16 + col16] = f2bf(pe);
            }
        }
        asm volatile("s_waitcnt lgkmcnt(0)" ::: "memory");

        const unsigned short* prow = &Pl[(qrow0 + col16) * 68];
        s4v p0l = *(const s4v*)(prow + quad * 8);
        s4v p0h = *(const s4v*)(prow + quad * 8 + 4);
        s4v p1l = *(const s4v*)(prow + 32 + quad * 8);
        s4v p1h = *(const s4v*)(prow + 36 + quad * 8);
        s8v pa0 = __builtin_shufflevector(p0l, p0h, 0, 1, 2, 3, 4, 5, 6, 7);
        s8v pa1 = __builtin_shufflevector(p1l, p1h, 0, 1, 2, 3, 4, 5, 6, 7);
#pragma unroll
        for (int nt = 0; nt < 4; ++nt) {
            s8v vb0 = *(const s8v*)&Vs[(nt * 16 + col16) * 72 + quad * 8];
            s8v vb1 = *(const s8v*)&Vs[(nt * 16 + col16) * 72 + 32 + quad * 8];
            o[nt] = __builtin_amdgcn_mfma_f32_16x16x32_bf16(pa0, vb0, o[nt], 0, 0, 0);
            o[nt] = __builtin_amdgcn_mfma_f32_16x16x32_bf16(pa1, vb1, o[nt], 0, 0, 0);
        }

        __syncthreads();
        if (kt < 15) {
            *(uint4*)&Ks[(e0 >> 6) * 72 + (e0 & 63)] = pk0;
            *(uint4*)&Ks[(e1 >> 6) * 72 + (e1 & 63)] = pk1;
            *(uint4*)&Vs[(e0 >> 6) * 72 + (e0 & 63)] = pv0;
            *(uint4*)&Vs[(e1 >> 6) * 72 + (e1 & 63)] = pv1;
        }
        __syncthreads();
    }

#pragma unroll
    for (int i = 0; i < 4; ++i) {
#pragma unroll
        for (int m = 8; m >= 1; m >>= 1) lp[i] += __shfl_xor(lp[i], m, 16);
    }
#pragma unroll
    for (int i = 0; i < 4; ++i) {
        float inv = 1.f / lp[i];
        int   qr  = q0 + qrow0 + quad * 4 + i;
        unsigned short* dst = Out + ((size_t)b * 1024 + qr) * 768 + h * 64;
#pragma unroll
        for (int nt = 0; nt < 4; ++nt)
            dst[nt * 16 + col16] = f2bf(o[nt][i] * inv);
    }
}

extern "C" void kernel_launch(void* const* d_in, const int* in_sizes, int n_in,
                              void* d_out, int out_size, void* d_ws, size_t ws_size,
                              hipStream_t stream) {
    const float* x      = (const float*)d_in[0];
    const float* qkv_w  = (const float*)d_in[1];
    const float* qkv_b  = (const float*)d_in[2];
    const float* proj_w = (const float*)d_in[3];
    const float* proj_b = (const float*)d_in[4];
    const float* rel_h  = (const float*)d_in[5];
    const float* rel_w  = (const float*)d_in[6];
    float* out = (float*)d_out;

    char* ws = (char*)d_ws;
    unsigned short* qbuf  = (unsigned short*)(ws);             // bf16 [96][1024][64] 12582912
    unsigned short* kbuf  = (unsigned short*)(ws + 12582912);  // bf16 [96][1024][64] 12582912
    unsigned short* vtbuf = (unsigned short*)(ws + 25165824);  // bf16 [96][64][1024] 12582912
    unsigned short* xab   = (unsigned short*)(ws + 37748736);  // bf16 x / attn-out   12582912
    unsigned short* wqb   = (unsigned short*)(ws + 50331648);  // bf16 qkv_w          3538944
    unsigned short* wpb   = (unsigned short*)(ws + 53870592);  // bf16 proj_w         1179648
    unsigned short* qhb   = (unsigned short*)(ws + 55050240);  // bf16 [96][1024][32] 6291456
    unsigned short* qwb   = (unsigned short*)(ws + 61341696);  // bf16 [96][1024][32] 6291456

    to_bf16_all<<<4224, 256, 0, stream>>>(x, qkv_w, proj_w, xab, wqb, wpb);
    qkv_gemm_mfma<<<dim3(18, 64), 256, 0, stream>>>(xab, wqb, qkv_b, qbuf, kbuf, vtbuf);
    bias_prep_mfma<<<dim3(8, 96), 256, 0, stream>>>(qbuf, rel_h, rel_w, qhb, qwb);
    attn_mfma<<<1536, 256, 0, stream>>>(qbuf, kbuf, vtbuf, qhb, qwb, xab);
    proj_gemm_mfma<<<dim3(6, 64), 256, 0, stream>>>(xab, wpb, proj_b, out);
}